// Round 2
// baseline (464.221 us; speedup 1.0000x reference)
//
#include <hip/hip_runtime.h>
#include <hip/hip_bf16.h>

constexpr int kS   = 32;
constexpr int kB   = 256;
constexpr int kIN  = 1024;
constexpr int kOUT = 1024;
constexpr int OT   = 32;   // o-tile per block -> grid 32x32 = 1024 blocks (4/CU)

typedef __bf16 v4bf __attribute__((ext_vector_type(4)));
typedef __bf16 v8bf __attribute__((ext_vector_type(8)));
typedef float  v4f  __attribute__((ext_vector_type(4)));

__device__ __forceinline__ float softplus_f(float x) {
    return fmaxf(x, 0.0f) + log1pf(expf(-fabsf(x)));
}

__device__ __forceinline__ v4bf cvt4(float4 v) {
    v4bf r;
    r.x = (__bf16)v.x; r.y = (__bf16)v.y; r.z = (__bf16)v.z; r.w = (__bf16)v.w;
    return r;
}

__global__ void sigma_kernel(const float* __restrict__ rho, float* __restrict__ sigma) {
    int i = blockIdx.x * blockDim.x + threadIdx.x;
    sigma[i] = softplus_f(rho[i]);
}

__global__ void bias_kernel(const float* __restrict__ b_mu, const float* __restrict__ b_rho,
                            const float* __restrict__ eps_b, float* __restrict__ bias_s) {
    int i = blockIdx.x * blockDim.x + threadIdx.x;  // i = s*OUT + o
    int o = i & (kOUT - 1);
    bias_s[i] = fmaf(softplus_f(b_rho[o]), eps_b[i], b_mu[o]);
}

// cast X (S*B*IN fp32) -> bf16 workspace, 8 elems/thread
__global__ void xcast_kernel(const float* __restrict__ X, __bf16* __restrict__ Xb) {
    size_t i = ((size_t)blockIdx.x * blockDim.x + threadIdx.x) * 8;
    float4 a = *reinterpret_cast<const float4*>(X + i);
    float4 b = *reinterpret_cast<const float4*>(X + i + 4);
    v8bf r;
    r[0] = (__bf16)a.x; r[1] = (__bf16)a.y; r[2] = (__bf16)a.z; r[3] = (__bf16)a.w;
    r[4] = (__bf16)b.x; r[5] = (__bf16)b.y; r[6] = (__bf16)b.z; r[7] = (__bf16)b.w;
    *reinterpret_cast<v8bf*>(Xb + i) = r;
}

// Per block (s, o_tile of 32): out[s, 0:256, o_base:o_base+32]
// Register-prefetch double-buffered staging: loads for tile k+1 are issued
// before the MFMA phase of tile k, so the vmcnt drain overlaps compute.
template<bool XBF>
__global__ __launch_bounds__(256, 4) void dv_main(
        const void* __restrict__ Xv,     // [S][B][IN] (bf16 if XBF else fp32)
        const float* __restrict__ Wmu,   // [OUT][IN]
        const float* __restrict__ Wsig,  // [OUT][IN]
        const float* __restrict__ Ew,    // [S][OUT][IN]
        const float* __restrict__ Bs,    // [S][OUT]
        float* __restrict__ O)           // [S][B][OUT]
{
    constexpr int LS = 40;  // LDS row stride (80 B): 16B-aligned, spreads banks
    __shared__ __attribute__((aligned(16))) __bf16 Xs[256 * LS];  // 20 KB
    __shared__ __attribute__((aligned(16))) __bf16 Ws[OT * LS];   // 2.5 KB

    const int tid    = threadIdx.x;
    const int ot     = blockIdx.x;       // 0..31
    const int s      = blockIdx.y;       // 0..31
    const int o_base = ot * OT;
    const int lane   = tid & 63;
    const int wv     = tid >> 6;
    const int lr     = lane & 15;
    const int kg     = lane >> 4;
    const int m_base = wv * 64;

    const float* Eg = Ew   + ((size_t)s * kOUT + o_base) * kIN;
    const float* Mg = Wmu  + (size_t)o_base * kIN;
    const float* Sg = Wsig + (size_t)o_base * kIN;
    const int wrow = tid >> 3;   // 0..31
    const int wkq  = tid & 7;

    v4f acc[4][2] = {};

    // prefetch registers
    uint4  xr_b[4];
    float4 xr_f[8];
    float4 we, wm, wg;

    auto issue = [&](int kk) {
        if constexpr (XBF) {
            const __bf16* Xb = (const __bf16*)Xv + (size_t)s * kB * kIN;
            #pragma unroll
            for (int j = 0; j < 4; ++j) {
                int f = j * 256 + tid, row = f >> 2, c = f & 3;
                xr_b[j] = *reinterpret_cast<const uint4*>(Xb + (size_t)row * kIN + kk + c * 8);
            }
        } else {
            const float* Xg = (const float*)Xv + (size_t)s * kB * kIN;
            #pragma unroll
            for (int j = 0; j < 8; ++j) {
                int f = j * 256 + tid, row = f >> 3, kq = f & 7;
                xr_f[j] = *reinterpret_cast<const float4*>(Xg + (size_t)row * kIN + kk + kq * 4);
            }
        }
        size_t widx = (size_t)wrow * kIN + kk + wkq * 4;
        we = *reinterpret_cast<const float4*>(Eg + widx);
        wm = *reinterpret_cast<const float4*>(Mg + widx);
        wg = *reinterpret_cast<const float4*>(Sg + widx);
    };

    issue(0);

    for (int kk = 0; kk < kIN; kk += 32) {
        // --- write staged tile to LDS (waits on in-flight loads here) ---
        if constexpr (XBF) {
            #pragma unroll
            for (int j = 0; j < 4; ++j) {
                int f = j * 256 + tid, row = f >> 2, c = f & 3;
                *reinterpret_cast<uint4*>(&Xs[row * LS + c * 8]) = xr_b[j];
            }
        } else {
            #pragma unroll
            for (int j = 0; j < 8; ++j) {
                int f = j * 256 + tid, row = f >> 3, kq = f & 7;
                *reinterpret_cast<v4bf*>(&Xs[row * LS + kq * 4]) = cvt4(xr_f[j]);
            }
        }
        float4 w;
        w.x = fmaf(wg.x, we.x, wm.x);
        w.y = fmaf(wg.y, we.y, wm.y);
        w.z = fmaf(wg.z, we.z, wm.z);
        w.w = fmaf(wg.w, we.w, wm.w);
        *reinterpret_cast<v4bf*>(&Ws[wrow * LS + wkq * 4]) = cvt4(w);

        // --- issue next tile's loads before compute (in flight across MFMA) ---
        if (kk + 32 < kIN) issue(kk + 32);

        __syncthreads();

        v8bf a[4], b[2];
        #pragma unroll
        for (int mf = 0; mf < 4; ++mf)
            a[mf] = *reinterpret_cast<const v8bf*>(&Xs[(m_base + mf * 16 + lr) * LS + kg * 8]);
        #pragma unroll
        for (int nf = 0; nf < 2; ++nf)
            b[nf] = *reinterpret_cast<const v8bf*>(&Ws[(nf * 16 + lr) * LS + kg * 8]);
        #pragma unroll
        for (int mf = 0; mf < 4; ++mf) {
            #pragma unroll
            for (int nf = 0; nf < 2; ++nf)
                acc[mf][nf] = __builtin_amdgcn_mfma_f32_16x16x32_bf16(a[mf], b[nf], acc[mf][nf], 0, 0, 0);
        }
        __syncthreads();
    }

    // --- epilogue: sampled bias + store ---
    float bias[2];
    #pragma unroll
    for (int nf = 0; nf < 2; ++nf)
        bias[nf] = Bs[(size_t)s * kOUT + o_base + nf * 16 + lr];

    #pragma unroll
    for (int mf = 0; mf < 4; ++mf) {
        #pragma unroll
        for (int r = 0; r < 4; ++r) {
            int brow = m_base + mf * 16 + kg * 4 + r;   // C/D: row=(lane>>4)*4+reg
            float* orow = O + ((size_t)s * kB + brow) * kOUT + o_base;
            #pragma unroll
            for (int nf = 0; nf < 2; ++nf)
                orow[nf * 16 + lr] = acc[mf][nf][r] + bias[nf];
        }
    }
}

extern "C" void kernel_launch(void* const* d_in, const int* in_sizes, int n_in,
                              void* d_out, int out_size, void* d_ws, size_t ws_size,
                              hipStream_t stream) {
    const float* input = (const float*)d_in[0];
    const float* w_mu  = (const float*)d_in[1];
    const float* w_rho = (const float*)d_in[2];
    const float* b_mu  = (const float*)d_in[3];
    const float* b_rho = (const float*)d_in[4];
    const float* eps_w = (const float*)d_in[5];
    const float* eps_b = (const float*)d_in[6];
    float* out = (float*)d_out;

    const size_t xbf_bytes   = (size_t)kS * kB * kIN * sizeof(__bf16);   // 16 MB
    const size_t sigma_bytes = (size_t)kOUT * kIN * sizeof(float);       //  4 MB
    const size_t bias_bytes  = (size_t)kS * kOUT * sizeof(float);        // 128 KB
    const bool use_xbf = ws_size >= xbf_bytes + sigma_bytes + bias_bytes;

    char* wsb = (char*)d_ws;
    __bf16* xbf   = (__bf16*)wsb;
    float*  sigma = use_xbf ? (float*)(wsb + xbf_bytes) : (float*)wsb;
    float*  bias_s = (float*)((char*)sigma + sigma_bytes);

    sigma_kernel<<<dim3((kOUT * kIN) / 256), 256, 0, stream>>>(w_rho, sigma);
    bias_kernel<<<dim3((kS * kOUT) / 256), 256, 0, stream>>>(b_mu, b_rho, eps_b, bias_s);

    dim3 grid(kOUT / OT, kS);
    if (use_xbf) {
        xcast_kernel<<<dim3((size_t)kS * kB * kIN / (256 * 8)), 256, 0, stream>>>(input, xbf);
        dv_main<true><<<grid, 256, 0, stream>>>(xbf, w_mu, sigma, eps_w, bias_s, out);
    } else {
        dv_main<false><<<grid, 256, 0, stream>>>(input, w_mu, sigma, eps_w, bias_s, out);
    }
}

// Round 3
// 335.467 us; speedup vs baseline: 1.3838x; 1.3838x over previous
//
#include <hip/hip_runtime.h>
#include <hip/hip_bf16.h>

constexpr int kS   = 32;
constexpr int kB   = 256;
constexpr int kIN  = 1024;
constexpr int kOUT = 1024;

typedef __bf16 v4bf __attribute__((ext_vector_type(4)));
typedef __bf16 v8bf __attribute__((ext_vector_type(8)));
typedef float  v4f  __attribute__((ext_vector_type(4)));

__device__ __forceinline__ float softplus_f(float x) {
    return fmaxf(x, 0.0f) + log1pf(expf(-fabsf(x)));
}
__device__ __forceinline__ unsigned int bfbits(float x) {
    __bf16 h = (__bf16)x;
    unsigned short u;
    __builtin_memcpy(&u, &h, 2);
    return (unsigned int)u;
}
__device__ __forceinline__ float asf(unsigned int u) {
    float f; __builtin_memcpy(&f, &u, 4); return f;
}

// pack (bf16(mu), bf16(softplus(rho))) into one u32 per weight element
__global__ void sigma_pack(const float* __restrict__ mu, const float* __restrict__ rho,
                           uint4* __restrict__ ms) {
    int gid = blockIdx.x * blockDim.x + threadIdx.x;    // 4 elems/thread
    float4 m = reinterpret_cast<const float4*>(mu)[gid];
    float4 r = reinterpret_cast<const float4*>(rho)[gid];
    uint4 o;
    o.x = bfbits(m.x) | (bfbits(softplus_f(r.x)) << 16);
    o.y = bfbits(m.y) | (bfbits(softplus_f(r.y)) << 16);
    o.z = bfbits(m.z) | (bfbits(softplus_f(r.z)) << 16);
    o.w = bfbits(m.w) | (bfbits(softplus_f(r.w)) << 16);
    ms[gid] = o;
}

// cast X (S*B*IN fp32) -> bf16 workspace, 8 elems/thread
__global__ void xcast_kernel(const float* __restrict__ X, __bf16* __restrict__ Xb) {
    size_t i = ((size_t)blockIdx.x * blockDim.x + threadIdx.x) * 8;
    float4 a = *reinterpret_cast<const float4*>(X + i);
    float4 b = *reinterpret_cast<const float4*>(X + i + 4);
    v8bf r;
    r[0] = (__bf16)a.x; r[1] = (__bf16)a.y; r[2] = (__bf16)a.z; r[3] = (__bf16)a.w;
    r[4] = (__bf16)b.x; r[5] = (__bf16)b.y; r[6] = (__bf16)b.z; r[7] = (__bf16)b.w;
    *reinterpret_cast<v8bf*>(Xb + i) = r;
}

// Block tile: M=128 (half of B), N=64 o-cols, BK=32, double-buffered LDS.
// Grid 1024: swizzle pairs mt=0/1 blocks exactly 8 apart (same XCD) so the
// shared eps_w tile dedupes in that XCD's L2.
template<bool XBF>
__global__ __launch_bounds__(256) void dv_main(
        const void* __restrict__ Xv,            // [S][B][IN] bf16 (XBF) or fp32
        const unsigned int* __restrict__ MS,    // [OUT][IN] packed (mu,sigma) bf16x2
        const float* __restrict__ Ew,           // [S][OUT][IN]
        const float* __restrict__ Bmu,          // [OUT]
        const float* __restrict__ Brho,         // [OUT]
        const float* __restrict__ Eb,           // [S][OUT]
        float* __restrict__ O)                  // [S][B][OUT]
{
    constexpr int LS = 40;  // LDS row stride in bf16 (80 B): 16B-aligned, 2-way banks (free)
    __shared__ __attribute__((aligned(16))) __bf16 Xs[2][128 * LS];  // 2 x 10 KB
    __shared__ __attribute__((aligned(16))) __bf16 Ws[2][64 * LS];   // 2 x  5 KB

    const int tid = threadIdx.x;
    const int bb  = blockIdx.x;
    const int rr_ = bb & 15, gg = bb >> 4;
    const int pid = gg * 8 + (rr_ & 7);   // 0..511 -> (s, ot)
    const int mt  = rr_ >> 3;             // 0/1, pair-blocks 8 apart -> same XCD
    const int s   = pid >> 4;             // 0..31
    const int ot  = pid & 15;             // 0..15
    const int o_base = ot * 64;
    const int m_glob = mt * 128;

    const int lane = tid & 63, wv = tid >> 6;
    const int lr = lane & 15, kg = lane >> 4;

    // W staging mapping: 512 slots = 64 rows x 8 float4-cols; 2 slots/thread
    const int wrow0 = tid >> 3;          // slot j*256+tid -> row = slot>>3
    const int wc    = tid & 7;
    const float*        Eg  = Ew + ((size_t)s * kOUT + o_base) * kIN;
    const unsigned int* MSg = MS + (size_t)o_base * kIN;

    v4f acc[2][4] = {};

    // prefetch registers
    uint4  xr[2];    // XBF: 512 slots = 128 rows x 4 x16B; 2/thread
    float4 xf[4];    // fp32: 1024 slots = 128 rows x 8 float4; 4/thread
    float4 er[2];
    uint4  pr[2];

#define STAGE_ISSUE(KK)                                                          \
    {                                                                            \
        if constexpr (XBF) {                                                     \
            const __bf16* Xb = (const __bf16*)Xv + ((size_t)s * kB + m_glob) * kIN; \
            _Pragma("unroll")                                                    \
            for (int j = 0; j < 2; ++j) {                                        \
                int slot = j * 256 + tid, row = slot >> 2, c = slot & 3;         \
                xr[j] = *reinterpret_cast<const uint4*>(Xb + (size_t)row * kIN + (KK) + c * 8); \
            }                                                                    \
        } else {                                                                 \
            const float* Xg = (const float*)Xv + ((size_t)s * kB + m_glob) * kIN; \
            _Pragma("unroll")                                                    \
            for (int j = 0; j < 4; ++j) {                                        \
                int slot = j * 256 + tid, row = slot >> 3, c = slot & 7;         \
                xf[j] = *reinterpret_cast<const float4*>(Xg + (size_t)row * kIN + (KK) + c * 4); \
            }                                                                    \
        }                                                                        \
        _Pragma("unroll")                                                        \
        for (int j = 0; j < 2; ++j) {                                            \
            int row = j * 32 + wrow0;                                            \
            er[j] = *reinterpret_cast<const float4*>(Eg + (size_t)row * kIN + (KK) + wc * 4); \
            pr[j] = *reinterpret_cast<const uint4*>(MSg + (size_t)row * kIN + (KK) + wc * 4); \
        }                                                                        \
    }

#define STAGE_STORE(P)                                                           \
    {                                                                            \
        if constexpr (XBF) {                                                     \
            _Pragma("unroll")                                                    \
            for (int j = 0; j < 2; ++j) {                                        \
                int slot = j * 256 + tid, row = slot >> 2, c = slot & 3;         \
                *reinterpret_cast<uint4*>(&Xs[P][row * LS + c * 8]) = xr[j];     \
            }                                                                    \
        } else {                                                                 \
            _Pragma("unroll")                                                    \
            for (int j = 0; j < 4; ++j) {                                        \
                int slot = j * 256 + tid, row = slot >> 3, c = slot & 7;         \
                v4bf w;                                                          \
                w[0] = (__bf16)xf[j].x; w[1] = (__bf16)xf[j].y;                  \
                w[2] = (__bf16)xf[j].z; w[3] = (__bf16)xf[j].w;                  \
                *reinterpret_cast<v4bf*>(&Xs[P][row * LS + c * 4]) = w;          \
            }                                                                    \
        }                                                                        \
        _Pragma("unroll")                                                        \
        for (int j = 0; j < 2; ++j) {                                            \
            int row = j * 32 + wrow0;                                            \
            v4bf w;                                                              \
            unsigned int p0 = pr[j].x, p1 = pr[j].y, p2 = pr[j].z, p3 = pr[j].w; \
            w[0] = (__bf16)fmaf(asf(p0 & 0xffff0000u), er[j].x, asf(p0 << 16));  \
            w[1] = (__bf16)fmaf(asf(p1 & 0xffff0000u), er[j].y, asf(p1 << 16));  \
            w[2] = (__bf16)fmaf(asf(p2 & 0xffff0000u), er[j].z, asf(p2 << 16));  \
            w[3] = (__bf16)fmaf(asf(p3 & 0xffff0000u), er[j].w, asf(p3 << 16));  \
            *reinterpret_cast<v4bf*>(&Ws[P][row * LS + wc * 4]) = w;             \
        }                                                                        \
    }

#define COMPUTE(P)                                                               \
    {                                                                            \
        v8bf a[2], bfr[4];                                                       \
        _Pragma("unroll")                                                        \
        for (int mf = 0; mf < 2; ++mf)                                           \
            a[mf] = *reinterpret_cast<const v8bf*>(&Xs[P][(wv * 32 + mf * 16 + lr) * LS + kg * 8]); \
        _Pragma("unroll")                                                        \
        for (int nf = 0; nf < 4; ++nf)                                           \
            bfr[nf] = *reinterpret_cast<const v8bf*>(&Ws[P][(nf * 16 + lr) * LS + kg * 8]); \
        _Pragma("unroll")                                                        \
        for (int mf = 0; mf < 2; ++mf)                                           \
            _Pragma("unroll")                                                    \
            for (int nf = 0; nf < 4; ++nf)                                       \
                acc[mf][nf] = __builtin_amdgcn_mfma_f32_16x16x32_bf16(a[mf], bfr[nf], acc[mf][nf], 0, 0, 0); \
    }

    STAGE_ISSUE(0);
    for (int kk = 0; kk < kIN; kk += 64) {
        // half 1: tile kk -> buf 0
        STAGE_STORE(0);
        STAGE_ISSUE(kk + 32);           // kk+32 <= 992 always valid
        __syncthreads();
        COMPUTE(0);
        // half 2: tile kk+32 -> buf 1
        STAGE_STORE(1);
        if (kk + 64 < kIN) STAGE_ISSUE(kk + 64);
        __syncthreads();
        COMPUTE(1);
    }

    // epilogue: sample bias inline, add, store
    float bias[4];
    #pragma unroll
    for (int nf = 0; nf < 4; ++nf) {
        int o = o_base + nf * 16 + lr;
        bias[nf] = fmaf(softplus_f(Brho[o]), Eb[(size_t)s * kOUT + o], Bmu[o]);
    }
    #pragma unroll
    for (int mf = 0; mf < 2; ++mf) {
        #pragma unroll
        for (int rr = 0; rr < 4; ++rr) {
            int mrow = m_glob + wv * 32 + mf * 16 + kg * 4 + rr;   // C/D row=(lane>>4)*4+reg
            float* orow = O + ((size_t)s * kB + mrow) * kOUT + o_base;
            #pragma unroll
            for (int nf = 0; nf < 4; ++nf)
                orow[nf * 16 + lr] = acc[mf][nf][rr] + bias[nf];   // col = lane&15
        }
    }
#undef STAGE_ISSUE
#undef STAGE_STORE
#undef COMPUTE
}

extern "C" void kernel_launch(void* const* d_in, const int* in_sizes, int n_in,
                              void* d_out, int out_size, void* d_ws, size_t ws_size,
                              hipStream_t stream) {
    const float* input = (const float*)d_in[0];
    const float* w_mu  = (const float*)d_in[1];
    const float* w_rho = (const float*)d_in[2];
    const float* b_mu  = (const float*)d_in[3];
    const float* b_rho = (const float*)d_in[4];
    const float* eps_w = (const float*)d_in[5];
    const float* eps_b = (const float*)d_in[6];
    float* out = (float*)d_out;

    const size_t ms_bytes  = (size_t)kOUT * kIN * 4;                 //  4 MB
    const size_t xbf_bytes = (size_t)kS * kB * kIN * sizeof(__bf16); // 16 MB
    const bool use_xbf = ws_size >= ms_bytes + xbf_bytes;

    unsigned int* ms = (unsigned int*)d_ws;
    __bf16* xbf = (__bf16*)((char*)d_ws + ms_bytes);

    sigma_pack<<<dim3((kOUT * kIN) / (256 * 4)), 256, 0, stream>>>(w_mu, w_rho, (uint4*)ms);

    dim3 grid(2 * 16 * kS);  // 1024 blocks, pair-swizzled
    if (use_xbf) {
        xcast_kernel<<<dim3((size_t)kS * kB * kIN / (256 * 8)), 256, 0, stream>>>(input, xbf);
        dv_main<true><<<grid, 256, 0, stream>>>(xbf, ms, eps_w, b_mu, b_rho, eps_b, out);
    } else {
        dv_main<false><<<grid, 256, 0, stream>>>(input, ms, eps_w, b_mu, b_rho, eps_b, out);
    }
}

// Round 4
// 295.431 us; speedup vs baseline: 1.5713x; 1.1355x over previous
//
#include <hip/hip_runtime.h>
#include <hip/hip_bf16.h>

constexpr int kS   = 32;
constexpr int kB   = 256;
constexpr int kIN  = 1024;
constexpr int kOUT = 1024;
constexpr int BN   = 32;   // o-cols per block
constexpr int BK   = 32;   // k per tile
constexpr int LS   = 40;   // Ws LDS row stride (bf16)

typedef __bf16 v4bf __attribute__((ext_vector_type(4)));
typedef __bf16 v8bf __attribute__((ext_vector_type(8)));
typedef float  v4f  __attribute__((ext_vector_type(4)));

__device__ __forceinline__ float softplus_f(float x) {
    return fmaxf(x, 0.0f) + log1pf(expf(-fabsf(x)));
}
__device__ __forceinline__ unsigned int bfbits(float x) {
    __bf16 h = (__bf16)x;
    unsigned short u;
    __builtin_memcpy(&u, &h, 2);
    return (unsigned int)u;
}
__device__ __forceinline__ float asf(unsigned int u) {
    float f; __builtin_memcpy(&f, &u, 4); return f;
}

// pack (bf16(mu) low, bf16(softplus(rho)) high) into u32 per weight element
__global__ void sigma_pack(const float* __restrict__ mu, const float* __restrict__ rho,
                           uint4* __restrict__ ms) {
    int gid = blockIdx.x * blockDim.x + threadIdx.x;  // 4 elems/thread
    float4 m = reinterpret_cast<const float4*>(mu)[gid];
    float4 r = reinterpret_cast<const float4*>(rho)[gid];
    uint4 o;
    o.x = bfbits(m.x) | (bfbits(softplus_f(r.x)) << 16);
    o.y = bfbits(m.y) | (bfbits(softplus_f(r.y)) << 16);
    o.z = bfbits(m.z) | (bfbits(softplus_f(r.z)) << 16);
    o.w = bfbits(m.w) | (bfbits(softplus_f(r.w)) << 16);
    ms[gid] = o;
}

// cast X fp32 -> bf16 workspace, 8 elems/thread
__global__ void xcast_kernel(const float* __restrict__ X, __bf16* __restrict__ Xb) {
    size_t i = ((size_t)blockIdx.x * blockDim.x + threadIdx.x) * 8;
    float4 a = *reinterpret_cast<const float4*>(X + i);
    float4 b = *reinterpret_cast<const float4*>(X + i + 4);
    v8bf r;
    r[0] = (__bf16)a.x; r[1] = (__bf16)a.y; r[2] = (__bf16)a.z; r[3] = (__bf16)a.w;
    r[4] = (__bf16)b.x; r[5] = (__bf16)b.y; r[6] = (__bf16)b.z; r[7] = (__bf16)b.w;
    *reinterpret_cast<v8bf*>(Xb + i) = r;
}

// async 16B/lane global->LDS (no result VGPRs)
#define GLDS16(g, l) __builtin_amdgcn_global_load_lds(                      \
    (const __attribute__((address_space(1))) void*)(g),                     \
    (__attribute__((address_space(3))) void*)(l), 16, 0, 0)

// Block: M=256 (all of B), N=32 o-cols, BK=32, double-buffered LDS,
// one barrier per K-tile. X staged async via global_load_lds (zero VGPRs);
// only the small W operand (eps + packed mu/sigma) is register-prefetched.
// XCD swizzle: blockIdx%8 selects XCD-group; each XCD owns s in {4x..4x+3}
// so X[s] bf16 (4 x 512 KB = 2 MB) stays L2-resident per XCD.
template<bool XBF>
__global__ __launch_bounds__(256, 4) void dv_main(
        const void* __restrict__ Xv,            // [S][B][IN] bf16 (XBF) or fp32
        const unsigned int* __restrict__ MS,    // [OUT][IN] packed (mu,sigma)
        const float* __restrict__ Ew,           // [S][OUT][IN]
        const float* __restrict__ Bmu,          // [OUT]
        const float* __restrict__ Brho,         // [OUT]
        const float* __restrict__ Eb,           // [S][OUT]
        float* __restrict__ O)                  // [S][B][OUT]
{
    // Xs: unpadded (global_load_lds-contiguous), quarter-swizzled by row>>2.
    __shared__ __attribute__((aligned(16))) __bf16 Xs[2][kB * BK];  // 2 x 16 KB
    __shared__ __attribute__((aligned(16))) __bf16 Ws[2][BN * LS];  // 2 x 2.5 KB

    const int tid  = threadIdx.x;
    const int bb   = blockIdx.x;
    const int xcd  = bb & 7;
    const int jj   = bb >> 3;                 // 0..127
    const int s    = (xcd << 2) | (jj >> 5);  // 0..31, clustered per XCD
    const int ot   = jj & 31;
    const int o_base = ot * BN;

    const int lane = tid & 63, wv = tid >> 6;
    const int lr = lane & 15, kg = lane >> 4;
    const int wrow = tid >> 3, wc = tid & 7;  // W staging: 32 rows x 8 float4

    const float*        Eg  = Ew + ((size_t)s * kOUT + o_base) * kIN;
    const unsigned int* MSg = MS + (size_t)o_base * kIN;
    const __bf16* Xb = (const __bf16*)Xv + (size_t)s * kB * kIN;
    const float*  Xg = (const float*)Xv + (size_t)s * kB * kIN;

    v4f acc[4][2] = {};
    float4 er;   // prefetched eps (4 fp32)
    uint4  pr;   // prefetched packed mu/sigma (4 u32)

    // ---- prologue: tile 0 ----
    if constexpr (XBF) {
        #pragma unroll
        for (int q = 0; q < 4; ++q) {
            int row = wv * 64 + q * 16 + (lane >> 2);
            int qg  = ((lane & 3) - (row >> 2)) & 3;     // inverse quarter-swizzle
            GLDS16(Xb + (size_t)row * kIN + qg * 8, &Xs[0][(wv * 64 + q * 16) * BK]);
        }
    }
    er = *reinterpret_cast<const float4*>(Eg + (size_t)wrow * kIN + wc * 4);
    pr = *reinterpret_cast<const uint4*>(MSg + (size_t)wrow * kIN + wc * 4);

    for (int kk = 0; kk < kIN; kk += BK) {
        const int p = (kk >> 5) & 1;

        // ---- stage W (tile kk) from prefetched regs ----
        {
            v4bf w;
            w[0] = (__bf16)fmaf(asf(pr.x & 0xffff0000u), er.x, asf(pr.x << 16));
            w[1] = (__bf16)fmaf(asf(pr.y & 0xffff0000u), er.y, asf(pr.y << 16));
            w[2] = (__bf16)fmaf(asf(pr.z & 0xffff0000u), er.z, asf(pr.z << 16));
            w[3] = (__bf16)fmaf(asf(pr.w & 0xffff0000u), er.w, asf(pr.w << 16));
            *reinterpret_cast<v4bf*>(&Ws[p][wrow * LS + wc * 4]) = w;
        }
        if constexpr (!XBF) {
            // fallback: synchronous fp32 X staging into the same swizzled layout
            #pragma unroll
            for (int f0 = 0; f0 < 8; ++f0) {
                int f = f0 * 256 + tid;
                int row = f >> 3, c = f & 7;
                float4 v = *reinterpret_cast<const float4*>(Xg + (size_t)row * kIN + kk + c * 4);
                int q = c >> 1, h = c & 1;
                int ql = (q + (row >> 2)) & 3;
                v4bf w;
                w[0] = (__bf16)v.x; w[1] = (__bf16)v.y; w[2] = (__bf16)v.z; w[3] = (__bf16)v.w;
                *reinterpret_cast<v4bf*>(&Xs[p][row * BK + ql * 8 + h * 4]) = w;
            }
        }
        __syncthreads();   // drains this tile's async X + makes Ws[p] visible

        // ---- issue next tile's loads (fly across compute + next stage) ----
        const int kk2 = kk + BK;
        if (kk2 < kIN) {
            const int p2 = p ^ 1;
            if constexpr (XBF) {
                #pragma unroll
                for (int q = 0; q < 4; ++q) {
                    int row = wv * 64 + q * 16 + (lane >> 2);
                    int qg  = ((lane & 3) - (row >> 2)) & 3;
                    GLDS16(Xb + (size_t)row * kIN + kk2 + qg * 8,
                           &Xs[p2][(wv * 64 + q * 16) * BK]);
                }
            }
            er = *reinterpret_cast<const float4*>(Eg + (size_t)wrow * kIN + kk2 + wc * 4);
            pr = *reinterpret_cast<const uint4*>(MSg + (size_t)wrow * kIN + kk2 + wc * 4);
        }

        // ---- compute on buf p ----
        v8bf a[4], b[2];
        #pragma unroll
        for (int mf = 0; mf < 4; ++mf) {
            int row = wv * 64 + mf * 16 + lr;
            int ql  = (kg + (row >> 2)) & 3;
            a[mf] = *reinterpret_cast<const v8bf*>(&Xs[p][row * BK + ql * 8]);
        }
        #pragma unroll
        for (int nf = 0; nf < 2; ++nf)
            b[nf] = *reinterpret_cast<const v8bf*>(&Ws[p][(nf * 16 + lr) * LS + kg * 8]);
        #pragma unroll
        for (int mf = 0; mf < 4; ++mf) {
            #pragma unroll
            for (int nf = 0; nf < 2; ++nf)
                acc[mf][nf] = __builtin_amdgcn_mfma_f32_16x16x32_bf16(a[mf], b[nf], acc[mf][nf], 0, 0, 0);
        }
    }

    // ---- epilogue: inline-sampled bias + store ----
    float bias[2];
    #pragma unroll
    for (int nf = 0; nf < 2; ++nf) {
        int o = o_base + nf * 16 + lr;
        bias[nf] = fmaf(softplus_f(Brho[o]), Eb[(size_t)s * kOUT + o], Bmu[o]);
    }
    #pragma unroll
    for (int mf = 0; mf < 4; ++mf) {
        #pragma unroll
        for (int rr = 0; rr < 4; ++rr) {
            int mrow = wv * 64 + mf * 16 + kg * 4 + rr;  // C/D: row=(lane>>4)*4+reg
            float* orow = O + ((size_t)s * kB + mrow) * kOUT + o_base;
            #pragma unroll
            for (int nf = 0; nf < 2; ++nf)
                orow[nf * 16 + lr] = acc[mf][nf][rr] + bias[nf];  // col = lane&15
        }
    }
}

extern "C" void kernel_launch(void* const* d_in, const int* in_sizes, int n_in,
                              void* d_out, int out_size, void* d_ws, size_t ws_size,
                              hipStream_t stream) {
    const float* input = (const float*)d_in[0];
    const float* w_mu  = (const float*)d_in[1];
    const float* w_rho = (const float*)d_in[2];
    const float* b_mu  = (const float*)d_in[3];
    const float* b_rho = (const float*)d_in[4];
    const float* eps_w = (const float*)d_in[5];
    const float* eps_b = (const float*)d_in[6];
    float* out = (float*)d_out;

    const size_t ms_bytes  = (size_t)kOUT * kIN * 4;                 //  4 MB
    const size_t xbf_bytes = (size_t)kS * kB * kIN * sizeof(__bf16); // 16 MB
    const bool use_xbf = ws_size >= ms_bytes + xbf_bytes;

    unsigned int* ms = (unsigned int*)d_ws;
    __bf16* xbf = (__bf16*)((char*)d_ws + ms_bytes);

    sigma_pack<<<dim3((kOUT * kIN) / (256 * 4)), 256, 0, stream>>>(w_mu, w_rho, (uint4*)ms);

    dim3 grid(kS * (kOUT / BN));   // 1024 blocks
    if (use_xbf) {
        xcast_kernel<<<dim3((size_t)kS * kB * kIN / (256 * 8)), 256, 0, stream>>>(input, xbf);
        dv_main<true><<<grid, 256, 0, stream>>>(xbf, ms, eps_w, b_mu, b_rho, eps_b, out);
    } else {
        dv_main<false><<<grid, 256, 0, stream>>>(input, ms, eps_w, b_mu, b_rho, eps_b, out);
    }
}

// Round 5
// 260.917 us; speedup vs baseline: 1.7792x; 1.1323x over previous
//
#include <hip/hip_runtime.h>
#include <hip/hip_bf16.h>

constexpr int kS   = 32;
constexpr int kB   = 256;
constexpr int kIN  = 1024;
constexpr int kOUT = 1024;
constexpr int BN   = 64;    // o-cols per block
constexpr int BK   = 32;    // k per MFMA tile
constexpr int CK   = 256;   // k per W-chunk (1 KB fp32 per eps row -> long DRAM bursts)

typedef __bf16 v4bf __attribute__((ext_vector_type(4)));
typedef __bf16 v8bf __attribute__((ext_vector_type(8)));
typedef float  v4f  __attribute__((ext_vector_type(4)));

__device__ __forceinline__ float softplus_f(float x) {
    return fmaxf(x, 0.0f) + log1pf(expf(-fabsf(x)));
}
__device__ __forceinline__ unsigned int bfbits(float x) {
    __bf16 h = (__bf16)x;
    unsigned short u;
    __builtin_memcpy(&u, &h, 2);
    return (unsigned int)u;
}
__device__ __forceinline__ float asf(unsigned int u) {
    float f; __builtin_memcpy(&f, &u, 4); return f;
}

// pack (bf16(mu) low, bf16(softplus(rho)) high) into u32 per weight element
__global__ void sigma_pack(const float* __restrict__ mu, const float* __restrict__ rho,
                           uint4* __restrict__ ms) {
    int gid = blockIdx.x * blockDim.x + threadIdx.x;  // 4 elems/thread
    float4 m = reinterpret_cast<const float4*>(mu)[gid];
    float4 r = reinterpret_cast<const float4*>(rho)[gid];
    uint4 o;
    o.x = bfbits(m.x) | (bfbits(softplus_f(r.x)) << 16);
    o.y = bfbits(m.y) | (bfbits(softplus_f(r.y)) << 16);
    o.z = bfbits(m.z) | (bfbits(softplus_f(r.z)) << 16);
    o.w = bfbits(m.w) | (bfbits(softplus_f(r.w)) << 16);
    ms[gid] = o;
}

// cast X fp32 -> bf16 workspace, 8 elems/thread
__global__ void xcast_kernel(const float* __restrict__ X, __bf16* __restrict__ Xb) {
    size_t i = ((size_t)blockIdx.x * blockDim.x + threadIdx.x) * 8;
    float4 a = *reinterpret_cast<const float4*>(X + i);
    float4 b = *reinterpret_cast<const float4*>(X + i + 4);
    v8bf r;
    r[0] = (__bf16)a.x; r[1] = (__bf16)a.y; r[2] = (__bf16)a.z; r[3] = (__bf16)a.w;
    r[4] = (__bf16)b.x; r[5] = (__bf16)b.y; r[6] = (__bf16)b.z; r[7] = (__bf16)b.w;
    *reinterpret_cast<v8bf*>(Xb + i) = r;
}

// async 16B/lane global->LDS (no result VGPRs)
#define GLDS16(g, l) __builtin_amdgcn_global_load_lds(                      \
    (const __attribute__((address_space(1))) void*)(g),                     \
    (__attribute__((address_space(3))) void*)(l), 16, 0, 0)

// Block: M=256 (all of B), N=64, K chunked 4 x 256.
// Per chunk: cooperatively materialize W (mu + sigma*eps -> bf16) into LDS,
// reading eps in 1 KB contiguous bursts per row (one wave-load per row) to
// stay DRAM-page friendly. Inner: 8 BK=32 MFMA tiles; X double-buffered via
// global_load_lds from the bf16 workspace (L2-resident via XCD swizzle).
template<bool XBF>
__global__ __launch_bounds__(256) void dv_main(
        const void* __restrict__ Xv,            // [S][B][IN] bf16 (XBF) or fp32
        const unsigned int* __restrict__ MS,    // [OUT][IN] packed (mu,sigma)
        const float* __restrict__ Ew,           // [S][OUT][IN]
        const float* __restrict__ Bmu,          // [OUT]
        const float* __restrict__ Brho,         // [OUT]
        const float* __restrict__ Eb,           // [S][OUT]
        float* __restrict__ O)                  // [S][B][OUT]
{
    __shared__ __attribute__((aligned(16))) __bf16 Xs[2][kB * BK];  // 2 x 16 KB
    __shared__ __attribute__((aligned(16))) __bf16 Wc[BN * CK];     // 32 KB, swizzled

    const int tid  = threadIdx.x;
    const int bb   = blockIdx.x;
    const int xcd  = bb & 7;
    const int jj   = bb >> 3;                  // 0..63
    const int s    = (xcd << 2) | (jj & 3);    // 4 s-values per XCD -> X L2-resident
    const int ot   = jj >> 2;                  // 0..15
    const int o_base = ot * BN;

    const int lane = tid & 63, wv = tid >> 6;
    const int lr = lane & 15, kg = lane >> 4;

    const float*        Eg  = Ew + ((size_t)s * kOUT + o_base) * kIN;
    const unsigned int* MSg = MS + (size_t)o_base * kIN;
    const __bf16* Xb = (const __bf16*)Xv + (size_t)s * kB * kIN;
    const float*  Xg = (const float*)Xv + (size_t)s * kB * kIN;

    v4f acc[4][4] = {};

    // X prologue: tile 0 -> Xs[0] (quarter-swizzled, verified layout from R4)
    if constexpr (XBF) {
        #pragma unroll
        for (int q = 0; q < 4; ++q) {
            int row = wv * 64 + q * 16 + (lane >> 2);
            int qg  = ((lane & 3) - (row >> 2)) & 3;
            GLDS16(Xb + (size_t)row * kIN + qg * 8, &Xs[0][(wv * 64 + q * 16) * BK]);
        }
    }

    for (int c = 0; c < 4; ++c) {
        const int ck = c * CK;

        // ---- materialize W chunk: 64 rows x 256 k, bf16, rotate-swizzled ----
        // slot8: 2048 slots = 64 rows x 32 chunks of 8 elems (16 B).
        // Each wave covers whole rows: 1 KB contiguous eps read per row.
        #pragma unroll 2
        for (int j = 0; j < 8; ++j) {
            int slot = j * 256 + tid;
            int row  = slot >> 5;          // 0..63
            int ch   = slot & 31;          // 8-elem chunk
            const float*        ep = Eg  + (size_t)row * kIN + ck + ch * 8;
            const unsigned int* mp = MSg + (size_t)row * kIN + ck + ch * 8;
            float4 e0 = *reinterpret_cast<const float4*>(ep);
            float4 e1 = *reinterpret_cast<const float4*>(ep + 4);
            uint4  p0 = *reinterpret_cast<const uint4*>(mp);
            uint4  p1 = *reinterpret_cast<const uint4*>(mp + 4);
            v8bf w;
            w[0] = (__bf16)fmaf(asf(p0.x & 0xffff0000u), e0.x, asf(p0.x << 16));
            w[1] = (__bf16)fmaf(asf(p0.y & 0xffff0000u), e0.y, asf(p0.y << 16));
            w[2] = (__bf16)fmaf(asf(p0.z & 0xffff0000u), e0.z, asf(p0.z << 16));
            w[3] = (__bf16)fmaf(asf(p0.w & 0xffff0000u), e0.w, asf(p0.w << 16));
            w[4] = (__bf16)fmaf(asf(p1.x & 0xffff0000u), e1.x, asf(p1.x << 16));
            w[5] = (__bf16)fmaf(asf(p1.y & 0xffff0000u), e1.y, asf(p1.y << 16));
            w[6] = (__bf16)fmaf(asf(p1.z & 0xffff0000u), e1.z, asf(p1.z << 16));
            w[7] = (__bf16)fmaf(asf(p1.w & 0xffff0000u), e1.w, asf(p1.w << 16));
            int pos = (ch + 2 * row) & 31;   // rotate-swizzle: 4-way max on reads
            *reinterpret_cast<v8bf*>(&Wc[row * CK + pos * 8]) = w;
        }
        __syncthreads();   // W chunk visible; also drains prologue/last X load

        // ---- 8 inner MFMA tiles ----
        for (int t = 0; t < 8; ++t) {
            const int kt = c * 8 + t;
            const int p  = kt & 1;

            if constexpr (XBF) {
                if (kt + 1 < 32) {
                    const int kk2 = (kt + 1) * BK;
                    #pragma unroll
                    for (int q = 0; q < 4; ++q) {
                        int row = wv * 64 + q * 16 + (lane >> 2);
                        int qg  = ((lane & 3) - (row >> 2)) & 3;
                        GLDS16(Xb + (size_t)row * kIN + kk2 + qg * 8,
                               &Xs[p ^ 1][(wv * 64 + q * 16) * BK]);
                    }
                }
            } else {
                // fallback: synchronous fp32 X staging for this tile
                #pragma unroll
                for (int f0 = 0; f0 < 8; ++f0) {
                    int f = f0 * 256 + tid;
                    int row = f >> 3, cc = f & 7;
                    float4 v = *reinterpret_cast<const float4*>(
                        Xg + (size_t)row * kIN + kt * BK + cc * 4);
                    int q = cc >> 1, h = cc & 1;
                    int ql = (q + (row >> 2)) & 3;
                    v4bf w;
                    w[0] = (__bf16)v.x; w[1] = (__bf16)v.y;
                    w[2] = (__bf16)v.z; w[3] = (__bf16)v.w;
                    *reinterpret_cast<v4bf*>(&Xs[p][row * BK + ql * 8 + h * 4]) = w;
                }
                __syncthreads();
            }

            v8bf a[4], b[4];
            #pragma unroll
            for (int mf = 0; mf < 4; ++mf) {
                int row = wv * 64 + mf * 16 + lr;
                int ql  = (kg + (row >> 2)) & 3;
                a[mf] = *reinterpret_cast<const v8bf*>(&Xs[p][row * BK + ql * 8]);
            }
            #pragma unroll
            for (int nf = 0; nf < 4; ++nf) {
                int r   = nf * 16 + lr;
                int pos = ((t * 4 + kg) + 2 * r) & 31;
                b[nf] = *reinterpret_cast<const v8bf*>(&Wc[r * CK + pos * 8]);
            }
            #pragma unroll
            for (int mf = 0; mf < 4; ++mf) {
                #pragma unroll
                for (int nf = 0; nf < 4; ++nf)
                    acc[mf][nf] = __builtin_amdgcn_mfma_f32_16x16x32_bf16(
                        a[mf], b[nf], acc[mf][nf], 0, 0, 0);
            }
            __syncthreads();   // protects Xs[p^1] write/read + Wc for next chunk
        }
    }

    // ---- epilogue: inline-sampled bias + store ----
    float bias[4];
    #pragma unroll
    for (int nf = 0; nf < 4; ++nf) {
        int o = o_base + nf * 16 + lr;
        bias[nf] = fmaf(softplus_f(Brho[o]), Eb[(size_t)s * kOUT + o], Bmu[o]);
    }
    #pragma unroll
    for (int mf = 0; mf < 4; ++mf) {
        #pragma unroll
        for (int rr = 0; rr < 4; ++rr) {
            int mrow = wv * 64 + mf * 16 + kg * 4 + rr;  // C/D: row=(lane>>4)*4+reg
            float* orow = O + ((size_t)s * kB + mrow) * kOUT + o_base;
            #pragma unroll
            for (int nf = 0; nf < 4; ++nf)
                orow[nf * 16 + lr] = acc[mf][nf][rr] + bias[nf];  // col = lane&15
        }
    }
}

extern "C" void kernel_launch(void* const* d_in, const int* in_sizes, int n_in,
                              void* d_out, int out_size, void* d_ws, size_t ws_size,
                              hipStream_t stream) {
    const float* input = (const float*)d_in[0];
    const float* w_mu  = (const float*)d_in[1];
    const float* w_rho = (const float*)d_in[2];
    const float* b_mu  = (const float*)d_in[3];
    const float* b_rho = (const float*)d_in[4];
    const float* eps_w = (const float*)d_in[5];
    const float* eps_b = (const float*)d_in[6];
    float* out = (float*)d_out;

    const size_t ms_bytes  = (size_t)kOUT * kIN * 4;                 //  4 MB
    const size_t xbf_bytes = (size_t)kS * kB * kIN * sizeof(__bf16); // 16 MB
    const bool use_xbf = ws_size >= ms_bytes + xbf_bytes;

    unsigned int* ms = (unsigned int*)d_ws;
    __bf16* xbf = (__bf16*)((char*)d_ws + ms_bytes);

    sigma_pack<<<dim3((kOUT * kIN) / (256 * 4)), 256, 0, stream>>>(w_mu, w_rho, (uint4*)ms);

    dim3 grid(kS * (kOUT / BN));   // 512 blocks, XCD-swizzled
    if (use_xbf) {
        xcast_kernel<<<dim3((size_t)kS * kB * kIN / (256 * 8)), 256, 0, stream>>>(input, xbf);
        dv_main<true><<<grid, 256, 0, stream>>>(xbf, ms, eps_w, b_mu, b_rho, eps_b, out);
    } else {
        dv_main<false><<<grid, 256, 0, stream>>>(input, ms, eps_w, b_mu, b_rho, eps_b, out);
    }
}